// Round 4
// baseline (425.164 us; speedup 1.0000x reference)
//
#include <hip/hip_runtime.h>
#include <hip/hip_bf16.h>
#include <math.h>

#define B_NUM 2
#define S_LEN 4096
#define D_DIM 1024
#define H_NUM 16
#define DKH   64

typedef __attribute__((ext_vector_type(8))) short short8;   // 8 bf16 = 4 VGPR (MFMA A/B frag)
typedef __attribute__((ext_vector_type(4))) float f32x4;    // MFMA C/D frag

__device__ __forceinline__ unsigned short f2bf(float f) {
    unsigned int u = __float_as_uint(f);
    u = (u + 0x7FFFu + ((u >> 16) & 1u)) >> 16;   // RNE
    return (unsigned short)u;
}

// packed f32x2 -> bf16x2, RNE
__device__ __forceinline__ unsigned pk_bf16(float lo, float hi) {
    __hip_bfloat162 h = __float22bfloat162_rn(make_float2(lo, hi));
    unsigned u; __builtin_memcpy(&u, &h, 4); return u;
}

// async global->LDS, 16B per lane (GEMM staging)
__device__ __forceinline__ void async_ld16(const unsigned short* g, unsigned short* l) {
    __builtin_amdgcn_global_load_lds(
        (const __attribute__((address_space(1))) unsigned int*)g,
        (__attribute__((address_space(3))) unsigned int*)l, 16, 0, 0);
}

// ---------------------------------------------------------------------------
// fused fp32 -> bf16 converts
// ---------------------------------------------------------------------------
__global__ __launch_bounds__(256) void f2b_3(
    const float* __restrict__ x0, const float* __restrict__ x1, const float* __restrict__ x2,
    unsigned short* __restrict__ y0, unsigned short* __restrict__ y1, unsigned short* __restrict__ y2)
{
    const float* xs[3] = { x0, x1, x2 };
    unsigned short* ys[3] = { y0, y1, y2 };
    const float* x = xs[blockIdx.y];
    unsigned short* y = ys[blockIdx.y];
    int i = (blockIdx.x * 256 + threadIdx.x) * 8;
    float4 a = *(const float4*)(x + i);
    float4 b = *(const float4*)(x + i + 4);
    unsigned t[4] = { pk_bf16(a.x, a.y), pk_bf16(a.z, a.w),
                      pk_bf16(b.x, b.y), pk_bf16(b.z, b.w) };
    *(uint4*)(y + i) = *(const uint4*)t;
}
__global__ __launch_bounds__(256) void f2b_4(
    const float* __restrict__ x0, const float* __restrict__ x1,
    const float* __restrict__ x2, const float* __restrict__ x3,
    unsigned short* __restrict__ y0, unsigned short* __restrict__ y1,
    unsigned short* __restrict__ y2, unsigned short* __restrict__ y3)
{
    const float* xs[4] = { x0, x1, x2, x3 };
    unsigned short* ys[4] = { y0, y1, y2, y3 };
    const float* x = xs[blockIdx.y];
    unsigned short* y = ys[blockIdx.y];
    int i = (blockIdx.x * 256 + threadIdx.x) * 8;
    float4 a = *(const float4*)(x + i);
    float4 b = *(const float4*)(x + i + 4);
    unsigned t[4] = { pk_bf16(a.x, a.y), pk_bf16(a.z, a.w),
                      pk_bf16(b.x, b.y), pk_bf16(b.z, b.w) };
    *(uint4*)(y + i) = *(const uint4*)t;
}

// ---------------------------------------------------------------------------
// Shared GEMM core (m97 recipe, 128x128 tile) -- kept for gemm_out.
// ---------------------------------------------------------------------------
__device__ __forceinline__ void gemm_core(
    const unsigned short* __restrict__ A, const unsigned short* __restrict__ Wt,
    unsigned short* As, unsigned short* Bs,
    int m0, int n0, int K, f32x4 (&acc)[4][4])
{
    const int tid  = threadIdx.x;
    const int lane = tid & 63;
    const int wave = tid >> 6;
    const int quad = lane >> 4;
    const int l15  = lane & 15;
    const int wm = (wave >> 1) * 64;
    const int wn = (wave & 1) * 64;

    const int c0 = tid, c1 = tid + 256;
    const unsigned short* A0 = A  + (size_t)(m0 + (c0 >> 2)) * K + (c0 & 3) * 8;
    const unsigned short* A1 = A  + (size_t)(m0 + (c1 >> 2)) * K + (c1 & 3) * 8;
    const unsigned short* W0 = Wt + (size_t)(n0 + (c0 >> 2)) * K + (c0 & 3) * 8;
    const unsigned short* W1 = Wt + (size_t)(n0 + (c1 >> 2)) * K + (c1 & 3) * 8;

    for (int k0 = 0; k0 < K; k0 += 32) {
        __syncthreads();
        async_ld16(A0 + k0, &As[c0 * 8]);
        async_ld16(A1 + k0, &As[c1 * 8]);
        async_ld16(W0 + k0, &Bs[c0 * 8]);
        async_ld16(W1 + k0, &Bs[c1 * 8]);
        __syncthreads();

        short8 af[4], bfr[4];
        #pragma unroll
        for (int i = 0; i < 4; ++i)
            af[i] = *(const short8*)&As[(wm + i * 16 + l15) * 32 + quad * 8];
        #pragma unroll
        for (int j = 0; j < 4; ++j)
            bfr[j] = *(const short8*)&Bs[(wn + j * 16 + l15) * 32 + quad * 8];
        #pragma unroll
        for (int i = 0; i < 4; ++i)
            #pragma unroll
            for (int j = 0; j < 4; ++j)
                acc[i][j] = __builtin_amdgcn_mfma_f32_16x16x32_bf16(af[i], bfr[j], acc[i][j], 0, 0, 0);
    }
}

// ---------------------------------------------------------------------------
// Fused QKV projection v2: 256x256 tile, BK=64, 8 waves (2M x 4N), phased
// schedule with counted vmcnt (T3+T4), swizzled LDS (T2), setprio (T5).
// The m97 128-tile structure tops out ~900 TF; the 256-tile phased schedule
// is the documented escape (1563 TF @4k). Per K-tile: 4 phases, each
// {2 global_load_lds for tile t+1 | swizzled ds_read_b128 subtile |
//  s_barrier | 16 MFMA (one C-quadrant x K=64) | s_barrier}.
// ONE vmcnt(2) per K-tile (phase 0): own 8 loads of the CURRENT buffer are
// guaranteed complete while the 2 just-issued next-tile loads stay in
// flight across the barrier. Raw s_barrier (NOT __syncthreads -- that
// would emit vmcnt(0) and drain the pipeline). sched_barrier(0) pins
// ds_reads after the phase-0 barrier (hoist guard) and before the
// end-of-tile barrier (sink guard).
// Swizzle (rule #21, both-sides): linear LDS dest (global_load_lds
// requirement), INVERSE-swizzled per-lane GLOBAL source col-chunk
// (ch ^ (row&7)), and the same XOR on the ds_read side -> <=2-way bank
// conflicts (free). Grid (4, 32, 3) = 384 blocks, 1 block/CU (128 KB LDS).
// z==2 writes V^T exactly as before. q-projection folds (1/8)*log2(e).
// ---------------------------------------------------------------------------
__global__ __launch_bounds__(512, 2) void gemm_qkv256(
    const unsigned short* __restrict__ Qb, const unsigned short* __restrict__ Kb,
    const unsigned short* __restrict__ Vb,
    const unsigned short* __restrict__ Wq, const unsigned short* __restrict__ Wk,
    const unsigned short* __restrict__ Wv,
    unsigned short* __restrict__ qo, unsigned short* __restrict__ ko,
    unsigned short* __restrict__ vto)
{
    __shared__ unsigned short Ab[2][256 * 64];   // [row=m][k] 16B-chunk swizzled
    __shared__ unsigned short Bb[2][256 * 64];   // [row=n][k] 16B-chunk swizzled

    const int tid  = threadIdx.x;          // 0..511
    const int lane = tid & 63;
    const int wave = tid >> 6;             // 0..7
    const int quad = lane >> 4;
    const int l15  = lane & 15;
    const int wm2  = (wave >> 2) * 128;    // wave's 128-row block
    const int wn4  = (wave & 3) * 64;      // wave's 64-col block

    const int z = blockIdx.z;
    const unsigned short* A  = (z == 0) ? Qb : (z == 1) ? Kb : Vb;
    const unsigned short* Wt = (z == 0) ? Wq : (z == 1) ? Wk : Wv;
    const float scale = (z == 0) ? 0.125f * 1.4426950408889634f : 1.0f;

    const int m0 = blockIdx.y * 256;
    const int n0 = blockIdx.x * 256;

    // staging: load a in 0..3 covers rows [a*64, a*64+64); thread -> (row, ch)
    const int srow = tid >> 3;                       // 0..63 (+a*64)
    const int sch  = tid & 7;                        // 16B chunk 0..7
    const int gofs = (sch ^ (srow & 7)) * 8;         // inverse-swizzled src col (elems)
    const unsigned short* Asrc = A  + (size_t)(m0 + srow) * D_DIM + gofs;
    const unsigned short* Wsrc = Wt + (size_t)(n0 + srow) * D_DIM + gofs;
    const int ldst = tid * 8;                        // LDS elem offset (+a*4096)

    const f32x4 fzero = {0.f, 0.f, 0.f, 0.f};
    f32x4 acc[8][4];
    #pragma unroll
    for (int i = 0; i < 8; ++i)
        #pragma unroll
        for (int j = 0; j < 4; ++j) acc[i][j] = fzero;

    // ---- prologue: stage K-tile 0 into buffer 0 (8 loads/thread)
    #pragma unroll
    for (int a = 0; a < 4; ++a)
        async_ld16(Asrc + a * (64 * D_DIM), &Ab[0][a * 4096 + ldst]);
    #pragma unroll
    for (int a = 0; a < 4; ++a)
        async_ld16(Wsrc + a * (64 * D_DIM), &Bb[0][a * 4096 + ldst]);

    for (int kt = 0; kt < 16; ++kt) {
        const int p = kt & 1;
        const unsigned short* Ac = Ab[p];
        const unsigned short* Bc = Bb[p];
        unsigned short* An = Ab[p ^ 1];
        unsigned short* Bn = Bb[p ^ 1];
        const int kn = (kt + 1) * 64;     // next K-tile col base

        short8 afA[4][2], afB[4][2], bf01[2][2], bf23[2][2], bf01b[2][2];

        // ============ phase 0: quadrant (mi 0-3, nj 0-1) ============
        if (kt < 15) {
            async_ld16(Asrc + kn,                &An[0 * 4096 + ldst]);
            async_ld16(Asrc + kn + 64 * D_DIM,   &An[1 * 4096 + ldst]);
            asm volatile("s_waitcnt vmcnt(2)" ::: "memory");   // current buf's 8 done
        } else {
            asm volatile("s_waitcnt vmcnt(0)" ::: "memory");
        }
        __builtin_amdgcn_s_barrier();          // all waves' current-buf loads done
        __builtin_amdgcn_sched_barrier(0);     // pin ds_reads below the barrier

        #pragma unroll
        for (int mi = 0; mi < 4; ++mi)
            #pragma unroll
            for (int kk = 0; kk < 2; ++kk) {
                const int r = wm2 + mi * 16 + l15;
                afA[mi][kk] = *(const short8*)&Ac[r * 64 + (((kk * 4 + quad) ^ (r & 7)) << 3)];
            }
        #pragma unroll
        for (int nj = 0; nj < 2; ++nj)
            #pragma unroll
            for (int kk = 0; kk < 2; ++kk) {
                const int r = wn4 + nj * 16 + l15;
                bf01[nj][kk] = *(const short8*)&Bc[r * 64 + (((kk * 4 + quad) ^ (r & 7)) << 3)];
            }
        __builtin_amdgcn_s_setprio(1);
        #pragma unroll
        for (int kk = 0; kk < 2; ++kk)
            #pragma unroll
            for (int mi = 0; mi < 4; ++mi)
                #pragma unroll
                for (int nj = 0; nj < 2; ++nj)
                    acc[mi][nj] = __builtin_amdgcn_mfma_f32_16x16x32_bf16(
                        afA[mi][kk], bf01[nj][kk], acc[mi][nj], 0, 0, 0);
        __builtin_amdgcn_s_setprio(0);
        __builtin_amdgcn_s_barrier();

        // ============ phase 1: quadrant (mi 0-3, nj 2-3), reuse afA ============
        if (kt < 15) {
            async_ld16(Asrc + kn + 2 * 64 * D_DIM, &An[2 * 4096 + ldst]);
            async_ld16(Asrc + kn + 3 * 64 * D_DIM, &An[3 * 4096 + ldst]);
        }
        #pragma unroll
        for (int nj = 0; nj < 2; ++nj)
            #pragma unroll
            for (int kk = 0; kk < 2; ++kk) {
                const int r = wn4 + (2 + nj) * 16 + l15;
                bf23[nj][kk] = *(const short8*)&Bc[r * 64 + (((kk * 4 + quad) ^ (r & 7)) << 3)];
            }
        __builtin_amdgcn_s_setprio(1);
        #pragma unroll
        for (int kk = 0; kk < 2; ++kk)
            #pragma unroll
            for (int mi = 0; mi < 4; ++mi)
                #pragma unroll
                for (int nj = 0; nj < 2; ++nj)
                    acc[mi][2 + nj] = __builtin_amdgcn_mfma_f32_16x16x32_bf16(
                        afA[mi][kk], bf23[nj][kk], acc[mi][2 + nj], 0, 0, 0);
        __builtin_amdgcn_s_setprio(0);
        __builtin_amdgcn_s_barrier();

        // ============ phase 2: quadrant (mi 4-7, nj 2-3), reuse bf23 ============
        if (kt < 15) {
            async_ld16(Wsrc + kn,              &Bn[0 * 4096 + ldst]);
            async_ld16(Wsrc + kn + 64 * D_DIM, &Bn[1 * 4096 + ldst]);
        }
        #pragma unroll
        for (int mi = 0; mi < 4; ++mi)
            #pragma unroll
            for (int kk = 0; kk < 2; ++kk) {
                const int r = wm2 + (4 + mi) * 16 + l15;
                afB[mi][kk] = *(const short8*)&Ac[r * 64 + (((kk * 4 + quad) ^ (r & 7)) << 3)];
            }
        __builtin_amdgcn_s_setprio(1);
        #pragma unroll
        for (int kk = 0; kk < 2; ++kk)
            #pragma unroll
            for (int mi = 0; mi < 4; ++mi)
                #pragma unroll
                for (int nj = 0; nj < 2; ++nj)
                    acc[4 + mi][2 + nj] = __builtin_amdgcn_mfma_f32_16x16x32_bf16(
                        afB[mi][kk], bf23[nj][kk], acc[4 + mi][2 + nj], 0, 0, 0);
        __builtin_amdgcn_s_setprio(0);
        __builtin_amdgcn_s_barrier();

        // ============ phase 3: quadrant (mi 4-7, nj 0-1) ============
        if (kt < 15) {
            async_ld16(Wsrc + kn + 2 * 64 * D_DIM, &Bn[2 * 4096 + ldst]);
            async_ld16(Wsrc + kn + 3 * 64 * D_DIM, &Bn[3 * 4096 + ldst]);
        }
        #pragma unroll
        for (int nj = 0; nj < 2; ++nj)
            #pragma unroll
            for (int kk = 0; kk < 2; ++kk) {
                const int r = wn4 + nj * 16 + l15;
                bf01b[nj][kk] = *(const short8*)&Bc[r * 64 + (((kk * 4 + quad) ^ (r & 7)) << 3)];
            }
        __builtin_amdgcn_s_setprio(1);
        #pragma unroll
        for (int kk = 0; kk < 2; ++kk)
            #pragma unroll
            for (int mi = 0; mi < 4; ++mi)
                #pragma unroll
                for (int nj = 0; nj < 2; ++nj)
                    acc[4 + mi][nj] = __builtin_amdgcn_mfma_f32_16x16x32_bf16(
                        afB[mi][kk], bf01b[nj][kk], acc[4 + mi][nj], 0, 0, 0);
        __builtin_amdgcn_s_setprio(0);
        __builtin_amdgcn_sched_barrier(0);     // pin this tile's reads above
        __builtin_amdgcn_s_barrier();          // seal buf p before next tile writes it
        __builtin_amdgcn_sched_barrier(0);
    }

    // ---- epilogue ----
    if (z < 2) {
        unsigned short* out = (z == 0) ? qo : ko;
        #pragma unroll
        for (int mi = 0; mi < 8; ++mi)
            #pragma unroll
            for (int nj = 0; nj < 4; ++nj)
                #pragma unroll
                for (int r = 0; r < 4; ++r) {
                    const int row = m0 + wm2 + mi * 16 + quad * 4 + r;
                    const int col = n0 + wn4 + nj * 16 + l15;
                    out[(size_t)row * D_DIM + col] = f2bf(acc[mi][nj][r] * scale);
                }
    } else {
        // V^T: 4 accumulator regs = 4 consecutive s for one (h,dk) -> b64 store
        #pragma unroll
        for (int mi = 0; mi < 8; ++mi)
            #pragma unroll
            for (int nj = 0; nj < 4; ++nj) {
                const int row = m0 + wm2 + mi * 16 + quad * 4;   // s-global base
                const int col = n0 + wn4 + nj * 16 + l15;        // h*64 + dk
                const int bb = row >> 12, ss = row & (S_LEN - 1);
                uint2 u;
                u.x = pk_bf16(acc[mi][nj][0], acc[mi][nj][1]);
                u.y = pk_bf16(acc[mi][nj][2], acc[mi][nj][3]);
                *(uint2*)&vto[((size_t)(bb * H_NUM * DKH) + col) * S_LEN + ss] = u;
            }
    }
}

// ---------------------------------------------------------------------------
// Output-projection GEMM (fp32 out) -- m97 structure, unchanged (proven)
// ---------------------------------------------------------------------------
__global__ __launch_bounds__(256) void gemm_out(
    const unsigned short* __restrict__ A, const unsigned short* __restrict__ Wt,
    float* __restrict__ C)
{
    __shared__ unsigned short As[128 * 32];
    __shared__ unsigned short Bs[128 * 32];

    const int m0 = blockIdx.y * 128;
    const int n0 = blockIdx.x * 128;

    const f32x4 fzero = {0.f, 0.f, 0.f, 0.f};
    f32x4 acc[4][4];
    #pragma unroll
    for (int i = 0; i < 4; ++i)
        #pragma unroll
        for (int j = 0; j < 4; ++j) acc[i][j] = fzero;

    gemm_core(A, Wt, As, Bs, m0, n0, D_DIM, acc);

    const int lane = threadIdx.x & 63;
    const int wave = threadIdx.x >> 6;
    const int quad = lane >> 4;
    const int l15  = lane & 15;
    const int wm = (wave >> 1) * 64;
    const int wn = (wave & 1) * 64;

    #pragma unroll
    for (int i = 0; i < 4; ++i)
        #pragma unroll
        for (int j = 0; j < 4; ++j)
            #pragma unroll
            for (int r = 0; r < 4; ++r) {
                const int row = m0 + wm + i * 16 + quad * 4 + r;
                const int col = n0 + wn + j * 16 + l15;
                C[(size_t)row * D_DIM + col] = acc[i][j][r];
            }
}

// ---------------------------------------------------------------------------
// MFMA flash attention v7 (unchanged from round 3: 168 us, 818 TF).
// BR=256 per block, BC=64, grid 512, 512 threads (8 waves), each wave owns
// 32 q-rows. Ks/Vt double-buffered, one barrier per chunk, global prefetch
// one iteration ahead. S^T = K(A).Q^T(B); P packs to one b64 LDS store;
// lane-local row sums reduced with 2 shfl_xor at the end. PV: O^T =
// V^T(A).P^T(B), V pre-transposed in global by the V-GEMM. No-max exp2
// softmax. XOR swizzles keep LDS ops <=2-way. XCD-swizzled block decode.
// LDS: Ks 2x8K + Vt 2x8K + Ps 32K = 64 KB -> 2 blocks/CU, 16 waves/CU.
// ---------------------------------------------------------------------------
__global__ __launch_bounds__(512, 4) void flash_mfma(
    const unsigned short* __restrict__ q, const unsigned short* __restrict__ k,
    const unsigned short* __restrict__ vt, unsigned short* __restrict__ hp)
{
    __shared__ unsigned short Ks[2][64 * 64];    // [key][dk]   16B-chunk swizzled
    __shared__ unsigned short Vt[2][64 * 64];    // [dk][key]   16B-chunk swizzled
    __shared__ unsigned short Ps[256 * 64];      // [qrow][key] 8B-chunk even-swizzled

    const int tid  = threadIdx.x;
    const int lane = tid & 63;
    const int wave = tid >> 6;          // 0..7
    const int quad = lane >> 4;
    const int l15  = lane & 15;

    // XCD-aware decode: all 16 s-tiles of one (b,h) land on one XCD (d%8 map)
    const int bx   = blockIdx.x;
    const int xcd  = bx & 7, slot = bx >> 3;
    const int g    = xcd + 8 * (slot >> 4);   // (b*H + h), 0..31
    const int s0   = (slot & 15) * 256;
    const int b    = g >> 4, h = g & 15;
    const size_t base = (size_t)b * (S_LEN * D_DIM) + (size_t)h * DKH;
    const size_t vtb  = (size_t)g * (DKH * S_LEN);

    // Q fragments (B-operand): qf[nblk][kk], n = qrow = l15; wave owns 32 rows
    short8 qf[2][2];
    #pragma unroll
    for (int nb = 0; nb < 2; ++nb)
        #pragma unroll
        for (int kk = 0; kk < 2; ++kk)
            qf[nb][kk] = *(const short8*)(q + base +
                (size_t)(s0 + wave * 32 + nb * 16 + l15) * D_DIM + kk * 32 + quad * 8);

    const f32x4 fzero = {0.f, 0.f, 0.f, 0.f};
    f32x4 o[4][2];               // O^T: row=dk (quad*4+r), col=qrow (l15)
    float lacc[2] = {};
    #pragma unroll
    for (int i = 0; i < 4; ++i)
        #pragma unroll
        for (int j = 0; j < 2; ++j) o[i][j] = fzero;

    const int sr  = tid >> 3;          // staging row 0..63
    const int sch = tid & 7;           // 16B chunk index
    const int swz = ((sch ^ (sr & 7)) << 3);

    uint4 kpre, vpre;
    // ---- prologue: stage chunk 0 into buf 0, then issue prefetch of chunk 1
    {
        kpre = *(const uint4*)(k + base + (size_t)sr * D_DIM + sch * 8);
        vpre = *(const uint4*)(vt + vtb + (size_t)sr * S_LEN + sch * 8);
        *(uint4*)&Ks[0][sr * 64 + swz] = kpre;
        *(uint4*)&Vt[0][sr * 64 + swz] = vpre;
        kpre = *(const uint4*)(k + base + (size_t)(64 + sr) * D_DIM + sch * 8);
        vpre = *(const uint4*)(vt + vtb + (size_t)sr * S_LEN + 64 + sch * 8);
    }
    __syncthreads();

    for (int t0 = 0; t0 < S_LEN; t0 += 64) {
        const int cur = (t0 >> 6) & 1;
        const unsigned short* Kc = Ks[cur];
        const unsigned short* Vc = Vt[cur];

        // ---- stage chunk t+1 into the other buffer (data prefetched last
        // iter; vmcnt wait effectively free), then issue prefetch of t+2.
        if (t0 + 64 < S_LEN) {
            *(uint4*)&Ks[cur ^ 1][sr * 64 + swz] = kpre;
            *(uint4*)&Vt[cur ^ 1][sr * 64 + swz] = vpre;
            if (t0 + 128 < S_LEN) {
                kpre = *(const uint4*)(k + base + (size_t)(t0 + 128 + sr) * D_DIM + sch * 8);
                vpre = *(const uint4*)(vt + vtb + (size_t)sr * S_LEN + t0 + 128 + sch * 8);
            }
        }

        // ---- S^T = K . Q^T, in halves of 32 keys ----
        #pragma unroll
        for (int mh = 0; mh < 2; ++mh) {
            short8 kf[2][2];
            #pragma unroll
            for (int mi = 0; mi < 2; ++mi)
                #pragma unroll
                for (int kk = 0; kk < 2; ++kk) {
                    const int rr = (mh * 2 + mi) * 16 + l15;
                    kf[mi][kk] = *(const short8*)&Kc[rr * 64 + (((kk * 4 + quad) ^ (rr & 7)) << 3)];
                }
            f32x4 st[2][2];
            #pragma unroll
            for (int mi = 0; mi < 2; ++mi)
                #pragma unroll
                for (int nb = 0; nb < 2; ++nb) st[mi][nb] = fzero;
            __builtin_amdgcn_s_setprio(1);
            #pragma unroll
            for (int kk = 0; kk < 2; ++kk)
                #pragma unroll
                for (int mi = 0; mi < 2; ++mi)
                    #pragma unroll
                    for (int nb = 0; nb < 2; ++nb)
                        st[mi][nb] = __builtin_amdgcn_mfma_f32_16x16x32_bf16(
                            kf[mi][kk], qf[nb][kk], st[mi][nb], 0, 0, 0);
            __builtin_amdgcn_s_setprio(0);

            // p = exp2(s); lane-local row sums; pack 4 keys -> one b64 store
            #pragma unroll
            for (int mi = 0; mi < 2; ++mi)
                #pragma unroll
                for (int nb = 0; nb < 2; ++nb) {
                    float p0 = __builtin_amdgcn_exp2f(st[mi][nb][0]);
                    float p1 = __builtin_amdgcn_exp2f(st[mi][nb][1]);
                    float p2 = __builtin_amdgcn_exp2f(st[mi][nb][2]);
                    float p3 = __builtin_amdgcn_exp2f(st[mi][nb][3]);
                    lacc[nb] += (p0 + p1) + (p2 + p3);
                    uint2 u;
                    u.x = pk_bf16(p0, p1);
                    u.y = pk_bf16(p2, p3);
                    const int row = wave * 32 + nb * 16 + l15;
                    const int c8  = (mh * 2 + mi) * 4 + quad;          // 8B chunk
                    *(uint2*)&Ps[row * 64 + ((c8 ^ (l15 & 14)) << 2)] = u;
                }
        }

        // ---- O^T += V^T(A) . P^T(B) ----  (Ps rows wave-private: no barrier)
        #pragma unroll
        for (int kk = 0; kk < 2; ++kk) {
            short8 vf[4], pf[2];
            #pragma unroll
            for (int mb = 0; mb < 4; ++mb) {
                const int rv = mb * 16 + l15;
                vf[mb] = *(const short8*)&Vc[rv * 64 + (((kk * 4 + quad) ^ (rv & 7)) << 3)];
            }
            #pragma unroll
            for (int nb = 0; nb < 2; ++nb) {
                const int rp = wave * 32 + nb * 16 + l15;
                pf[nb] = *(const short8*)&Ps[rp * 64 + (((kk * 8 + quad * 2) ^ (l15 & 14)) << 2)];
            }
            __builtin_amdgcn_s_setprio(1);
            #pragma unroll
            for (int mb = 0; mb < 4; ++mb)
                #pragma unroll
                for (int nb = 0; nb < 2; ++nb)
                    o[mb][nb] = __builtin_amdgcn_mfma_f32_16x16x32_bf16(
                        vf[mb], pf[nb], o[mb][nb], 0, 0, 0);
            __builtin_amdgcn_s_setprio(0);
        }

        __syncthreads();   // next buffer staged + this buffer's reads done
    }

    // deferred l reduction (across the 4 quads sharing l15) + normalize + store
    #pragma unroll
    for (int nb = 0; nb < 2; ++nb) {
        float l = lacc[nb];
        l += __shfl_xor(l, 16);
        l += __shfl_xor(l, 32);
        const float inv = 1.f / l;
        const int row = s0 + wave * 32 + nb * 16 + l15;
        #pragma unroll
        for (int mb = 0; mb < 4; ++mb) {
            uint2 u;
            u.x = pk_bf16(o[mb][nb][0] * inv, o[mb][nb][1] * inv);
            u.y = pk_bf16(o[mb][nb][2] * inv, o[mb][nb][3] * inv);
            *(uint2*)&hp[base + (size_t)row * D_DIM + mb * 16 + quad * 4] = u;
        }
    }
}

// ---------------------------------------------------------------------------
extern "C" void kernel_launch(void* const* d_in, const int* in_sizes, int n_in,
                              void* d_out, int out_size, void* d_ws, size_t ws_size,
                              hipStream_t stream) {
    const float* Q  = (const float*)d_in[0];
    const float* K  = (const float*)d_in[1];
    const float* V  = (const float*)d_in[2];
    const float* Wq = (const float*)d_in[3];
    const float* Wk = (const float*)d_in[4];
    const float* Wv = (const float*)d_in[5];
    const float* Wo = (const float*)d_in[6];

    const int NBSD = 8388608;   // B*S*D
    const int NW   = 1048576;   // D*D

    unsigned short* Qb  = (unsigned short*)d_ws;
    unsigned short* Kb  = Qb  + NBSD;
    unsigned short* Vb  = Kb  + NBSD;
    unsigned short* Wqb = Vb  + NBSD;
    unsigned short* Wkb = Wqb + NW;
    unsigned short* Wvb = Wkb + NW;
    unsigned short* Wob = Wvb + NW;
    unsigned short* qp  = Wob + NW;
    unsigned short* kp  = qp  + NBSD;
    unsigned short* vtp = kp  + NBSD;   // V^T layout [(b*H+h)*64+dk][s]
    unsigned short* hb  = vtp + NBSD;   // total ~118 MB

    f2b_3<<<dim3(NBSD / 2048, 3), 256, 0, stream>>>(Q, K, V, Qb, Kb, Vb);
    f2b_4<<<dim3(NW / 2048, 4), 256, 0, stream>>>(Wq, Wk, Wv, Wo, Wqb, Wkb, Wvb, Wob);

    const int M = B_NUM * S_LEN;            // 8192
    dim3 gqkv(D_DIM / 256, M / 256, 3);     // 4 x 32 x 3 = 384 blocks
    gemm_qkv256<<<gqkv, 512, 0, stream>>>(Qb, Kb, Vb, Wqb, Wkb, Wvb, qp, kp, vtp);

    flash_mfma<<<512, 512, 0, stream>>>(qp, kp, vtp, hb);

    gemm_out<<<dim3(D_DIM / 128, M / 128), 256, 0, stream>>>(hb, Wob, (float*)d_out);
}

// Round 5
// 417.432 us; speedup vs baseline: 1.0185x; 1.0185x over previous
//
#include <hip/hip_runtime.h>
#include <hip/hip_bf16.h>
#include <math.h>

#define B_NUM 2
#define S_LEN 4096
#define D_DIM 1024
#define H_NUM 16
#define DKH   64

typedef __attribute__((ext_vector_type(8))) short short8;   // 8 bf16 = 4 VGPR (MFMA A/B frag)
typedef __attribute__((ext_vector_type(4))) float f32x4;    // MFMA C/D frag

__device__ __forceinline__ unsigned short f2bf(float f) {
    unsigned int u = __float_as_uint(f);
    u = (u + 0x7FFFu + ((u >> 16) & 1u)) >> 16;   // RNE
    return (unsigned short)u;
}

// packed f32x2 -> bf16x2, RNE
__device__ __forceinline__ unsigned pk_bf16(float lo, float hi) {
    __hip_bfloat162 h = __float22bfloat162_rn(make_float2(lo, hi));
    unsigned u; __builtin_memcpy(&u, &h, 4); return u;
}

// async global->LDS, 16B per lane (GEMM staging)
__device__ __forceinline__ void async_ld16(const unsigned short* g, unsigned short* l) {
    __builtin_amdgcn_global_load_lds(
        (const __attribute__((address_space(1))) unsigned int*)g,
        (__attribute__((address_space(3))) unsigned int*)l, 16, 0, 0);
}

// ---------------------------------------------------------------------------
// fused fp32 -> bf16 convert, ALL 7 arrays in one launch (fewer gaps).
// blocks 0..12287: Q/K/V (4096 blocks each); 12288..14335: Wq/Wk/Wv/Wo (512 each)
// ---------------------------------------------------------------------------
__global__ __launch_bounds__(256) void f2b_all(
    const float* __restrict__ x0, const float* __restrict__ x1, const float* __restrict__ x2,
    const float* __restrict__ x3, const float* __restrict__ x4, const float* __restrict__ x5,
    const float* __restrict__ x6,
    unsigned short* __restrict__ y0, unsigned short* __restrict__ y1, unsigned short* __restrict__ y2,
    unsigned short* __restrict__ y3, unsigned short* __restrict__ y4, unsigned short* __restrict__ y5,
    unsigned short* __restrict__ y6)
{
    const float* xs[7] = { x0, x1, x2, x3, x4, x5, x6 };
    unsigned short* ys[7] = { y0, y1, y2, y3, y4, y5, y6 };
    const int id = blockIdx.x;
    int a, off;
    if (id < 12288) { a = id >> 12;             off = id & 4095; }
    else            { a = 3 + ((id - 12288) >> 9); off = (id - 12288) & 511; }
    const float* x = xs[a];
    unsigned short* y = ys[a];
    int i = (off * 256 + threadIdx.x) * 8;
    float4 va = *(const float4*)(x + i);
    float4 vb = *(const float4*)(x + i + 4);
    unsigned t[4] = { pk_bf16(va.x, va.y), pk_bf16(va.z, va.w),
                      pk_bf16(vb.x, vb.y), pk_bf16(vb.z, vb.w) };
    *(uint4*)(y + i) = *(const uint4*)t;
}

// ---------------------------------------------------------------------------
// GEMM core v2: acc = A[M,K] @ W[N,K]^T for one 128x128 tile.
// T3-minimum 2-phase schedule (catalog recipe): LDS double-buffered
// (As/Bs each 2x[128x32]); per K-step: issue STAGE(t+1) FIRST, then
// ds_read+MFMA on buf t (covers the global_load_lds latency), then ONE
// __syncthreads (its implicit vmcnt(0) drain lands after compute, so the
// wait is near-free). Old core had stage fully EXPOSED between two
// barriers, twice per step. LDS 32 KB total -> occupancy unchanged
// (VGPR-limited ~3 blocks/CU).
// ---------------------------------------------------------------------------
__device__ __forceinline__ void gemm_core2(
    const unsigned short* __restrict__ A, const unsigned short* __restrict__ Wt,
    unsigned short* As, unsigned short* Bs,     // each 2*128*32 elems
    int m0, int n0, int K, f32x4 (&acc)[4][4])
{
    const int tid  = threadIdx.x;
    const int lane = tid & 63;
    const int wave = tid >> 6;
    const int quad = lane >> 4;
    const int l15  = lane & 15;
    const int wm = (wave >> 1) * 64;
    const int wn = (wave & 1) * 64;

    const int c0 = tid, c1 = tid + 256;
    const unsigned short* A0 = A  + (size_t)(m0 + (c0 >> 2)) * K + (c0 & 3) * 8;
    const unsigned short* A1 = A  + (size_t)(m0 + (c1 >> 2)) * K + (c1 & 3) * 8;
    const unsigned short* W0 = Wt + (size_t)(n0 + (c0 >> 2)) * K + (c0 & 3) * 8;
    const unsigned short* W1 = Wt + (size_t)(n0 + (c1 >> 2)) * K + (c1 & 3) * 8;

    // prologue: stage K-step 0 into half 0
    async_ld16(A0, &As[c0 * 8]);
    async_ld16(A1, &As[c1 * 8]);
    async_ld16(W0, &Bs[c0 * 8]);
    async_ld16(W1, &Bs[c1 * 8]);
    __syncthreads();

    for (int k0 = 0; k0 < K; k0 += 32) {
        const int cur = (k0 >> 5) & 1;
        const int cb  = cur * 4096;          // current half base (elems)

        // issue STAGE of step t+1 into the other half (in flight across MFMA)
        if (k0 + 32 < K) {
            const int nb = (cur ^ 1) * 4096;
            async_ld16(A0 + k0 + 32, &As[nb + c0 * 8]);
            async_ld16(A1 + k0 + 32, &As[nb + c1 * 8]);
            async_ld16(W0 + k0 + 32, &Bs[nb + c0 * 8]);
            async_ld16(W1 + k0 + 32, &Bs[nb + c1 * 8]);
        }

        short8 af[4], bfr[4];
        #pragma unroll
        for (int i = 0; i < 4; ++i)
            af[i] = *(const short8*)&As[cb + (wm + i * 16 + l15) * 32 + quad * 8];
        #pragma unroll
        for (int j = 0; j < 4; ++j)
            bfr[j] = *(const short8*)&Bs[cb + (wn + j * 16 + l15) * 32 + quad * 8];
        __builtin_amdgcn_s_setprio(1);
        #pragma unroll
        for (int i = 0; i < 4; ++i)
            #pragma unroll
            for (int j = 0; j < 4; ++j)
                acc[i][j] = __builtin_amdgcn_mfma_f32_16x16x32_bf16(af[i], bfr[j], acc[i][j], 0, 0, 0);
        __builtin_amdgcn_s_setprio(0);

        __syncthreads();   // drains vmcnt (next half staged) + seals cur reads
    }
}

// ---------------------------------------------------------------------------
// Fused QKV projection (m97 128x128 tile, gemm_core2). grid.z selects
// (A, W, out). z==2 (V) writes V^T global layout vt[(b*H+h)*64+dk][s] via
// packed b64 stores. q-projection folds (1/8)*log2(e) for exp2 softmax.
// ---------------------------------------------------------------------------
__global__ __launch_bounds__(256) void gemm_qkv(
    const unsigned short* __restrict__ Qb, const unsigned short* __restrict__ Kb,
    const unsigned short* __restrict__ Vb,
    const unsigned short* __restrict__ Wq, const unsigned short* __restrict__ Wk,
    const unsigned short* __restrict__ Wv,
    unsigned short* __restrict__ qo, unsigned short* __restrict__ ko,
    unsigned short* __restrict__ vto)
{
    __shared__ unsigned short As[2 * 128 * 32];
    __shared__ unsigned short Bs[2 * 128 * 32];

    const int z = blockIdx.z;
    const unsigned short* A  = (z == 0) ? Qb : (z == 1) ? Kb : Vb;
    const unsigned short* Wt = (z == 0) ? Wq : (z == 1) ? Wk : Wv;
    const float scale = (z == 0) ? 0.125f * 1.4426950408889634f : 1.0f;

    const int m0 = blockIdx.y * 128;
    const int n0 = blockIdx.x * 128;

    const f32x4 fzero = {0.f, 0.f, 0.f, 0.f};
    f32x4 acc[4][4];
    #pragma unroll
    for (int i = 0; i < 4; ++i)
        #pragma unroll
        for (int j = 0; j < 4; ++j) acc[i][j] = fzero;

    gemm_core2(A, Wt, As, Bs, m0, n0, D_DIM, acc);

    const int lane = threadIdx.x & 63;
    const int wave = threadIdx.x >> 6;
    const int quad = lane >> 4;
    const int l15  = lane & 15;
    const int wm = (wave >> 1) * 64;
    const int wn = (wave & 1) * 64;

    if (z < 2) {
        unsigned short* out = (z == 0) ? qo : ko;
        #pragma unroll
        for (int i = 0; i < 4; ++i)
            #pragma unroll
            for (int j = 0; j < 4; ++j)
                #pragma unroll
                for (int r = 0; r < 4; ++r) {
                    const int row = m0 + wm + i * 16 + quad * 4 + r;
                    const int col = n0 + wn + j * 16 + l15;
                    out[(size_t)row * D_DIM + col] = f2bf(acc[i][j][r] * scale);
                }
    } else {
        // V^T: 4 accumulator regs = 4 consecutive s for one (h,dk) -> b64 store
        #pragma unroll
        for (int i = 0; i < 4; ++i)
            #pragma unroll
            for (int j = 0; j < 4; ++j) {
                const int row = m0 + wm + i * 16 + quad * 4;   // s-global base (r=0)
                const int col = n0 + wn + j * 16 + l15;        // h*64 + dk
                const int bb = row >> 12, ss = row & (S_LEN - 1);
                uint2 u;
                u.x = pk_bf16(acc[i][j][0], acc[i][j][1]);
                u.y = pk_bf16(acc[i][j][2], acc[i][j][3]);
                *(uint2*)&vto[((size_t)(bb * H_NUM * DKH) + col) * S_LEN + ss] = u;
            }
    }
}

// ---------------------------------------------------------------------------
// Output-projection GEMM (fp32 out), gemm_core2
// ---------------------------------------------------------------------------
__global__ __launch_bounds__(256) void gemm_out(
    const unsigned short* __restrict__ A, const unsigned short* __restrict__ Wt,
    float* __restrict__ C)
{
    __shared__ unsigned short As[2 * 128 * 32];
    __shared__ unsigned short Bs[2 * 128 * 32];

    const int m0 = blockIdx.y * 128;
    const int n0 = blockIdx.x * 128;

    const f32x4 fzero = {0.f, 0.f, 0.f, 0.f};
    f32x4 acc[4][4];
    #pragma unroll
    for (int i = 0; i < 4; ++i)
        #pragma unroll
        for (int j = 0; j < 4; ++j) acc[i][j] = fzero;

    gemm_core2(A, Wt, As, Bs, m0, n0, D_DIM, acc);

    const int lane = threadIdx.x & 63;
    const int wave = threadIdx.x >> 6;
    const int quad = lane >> 4;
    const int l15  = lane & 15;
    const int wm = (wave >> 1) * 64;
    const int wn = (wave & 1) * 64;

    #pragma unroll
    for (int i = 0; i < 4; ++i)
        #pragma unroll
        for (int j = 0; j < 4; ++j)
            #pragma unroll
            for (int r = 0; r < 4; ++r) {
                const int row = m0 + wm + i * 16 + quad * 4 + r;
                const int col = n0 + wn + j * 16 + l15;
                C[(size_t)row * D_DIM + col] = acc[i][j][r];
            }
}

// ---------------------------------------------------------------------------
// MFMA flash attention v7 (unchanged: 170 us, 818 TF).
// BR=256 per block, BC=64, grid 512, 512 threads (8 waves), each wave owns
// 32 q-rows. Ks/Vt double-buffered, one barrier per chunk, global prefetch
// one iteration ahead. S^T = K(A).Q^T(B); P packs to one b64 LDS store;
// lane-local row sums reduced with 2 shfl_xor at the end. PV: O^T =
// V^T(A).P^T(B), V pre-transposed in global by the V-GEMM. No-max exp2
// softmax. XOR swizzles keep LDS ops <=2-way. XCD-swizzled block decode.
// LDS: Ks 2x8K + Vt 2x8K + Ps 32K = 64 KB -> 2 blocks/CU, 16 waves/CU.
// ---------------------------------------------------------------------------
__global__ __launch_bounds__(512, 4) void flash_mfma(
    const unsigned short* __restrict__ q, const unsigned short* __restrict__ k,
    const unsigned short* __restrict__ vt, unsigned short* __restrict__ hp)
{
    __shared__ unsigned short Ks[2][64 * 64];    // [key][dk]   16B-chunk swizzled
    __shared__ unsigned short Vt[2][64 * 64];    // [dk][key]   16B-chunk swizzled
    __shared__ unsigned short Ps[256 * 64];      // [qrow][key] 8B-chunk even-swizzled

    const int tid  = threadIdx.x;
    const int lane = tid & 63;
    const int wave = tid >> 6;          // 0..7
    const int quad = lane >> 4;
    const int l15  = lane & 15;

    // XCD-aware decode: all 16 s-tiles of one (b,h) land on one XCD (d%8 map)
    const int bx   = blockIdx.x;
    const int xcd  = bx & 7, slot = bx >> 3;
    const int g    = xcd + 8 * (slot >> 4);   // (b*H + h), 0..31
    const int s0   = (slot & 15) * 256;
    const int b    = g >> 4, h = g & 15;
    const size_t base = (size_t)b * (S_LEN * D_DIM) + (size_t)h * DKH;
    const size_t vtb  = (size_t)g * (DKH * S_LEN);

    // Q fragments (B-operand): qf[nblk][kk], n = qrow = l15; wave owns 32 rows
    short8 qf[2][2];
    #pragma unroll
    for (int nb = 0; nb < 2; ++nb)
        #pragma unroll
        for (int kk = 0; kk < 2; ++kk)
            qf[nb][kk] = *(const short8*)(q + base +
                (size_t)(s0 + wave * 32 + nb * 16 + l15) * D_DIM + kk * 32 + quad * 8);

    const f32x4 fzero = {0.f, 0.f, 0.f, 0.f};
    f32x4 o[4][2];               // O^T: row=dk (quad*4+r), col=qrow (l15)
    float lacc[2] = {};
    #pragma unroll
    for (int i = 0; i < 4; ++i)
        #pragma unroll
        for (int j = 0; j < 2; ++j) o[i][j] = fzero;

    const int sr  = tid >> 3;          // staging row 0..63
    const int sch = tid & 7;           // 16B chunk index
    const int swz = ((sch ^ (sr & 7)) << 3);

    uint4 kpre, vpre;
    // ---- prologue: stage chunk 0 into buf 0, then issue prefetch of chunk 1
    {
        kpre = *(const uint4*)(k + base + (size_t)sr * D_DIM + sch * 8);
        vpre = *(const uint4*)(vt + vtb + (size_t)sr * S_LEN + sch * 8);
        *(uint4*)&Ks[0][sr * 64 + swz] = kpre;
        *(uint4*)&Vt[0][sr * 64 + swz] = vpre;
        kpre = *(const uint4*)(k + base + (size_t)(64 + sr) * D_DIM + sch * 8);
        vpre = *(const uint4*)(vt + vtb + (size_t)sr * S_LEN + 64 + sch * 8);
    }
    __syncthreads();

    for (int t0 = 0; t0 < S_LEN; t0 += 64) {
        const int cur = (t0 >> 6) & 1;
        const unsigned short* Kc = Ks[cur];
        const unsigned short* Vc = Vt[cur];

        // ---- stage chunk t+1 into the other buffer (data prefetched last
        // iter; vmcnt wait effectively free), then issue prefetch of t+2.
        if (t0 + 64 < S_LEN) {
            *(uint4*)&Ks[cur ^ 1][sr * 64 + swz] = kpre;
            *(uint4*)&Vt[cur ^ 1][sr * 64 + swz] = vpre;
            if (t0 + 128 < S_LEN) {
                kpre = *(const uint4*)(k + base + (size_t)(t0 + 128 + sr) * D_DIM + sch * 8);
                vpre = *(const uint4*)(vt + vtb + (size_t)sr * S_LEN + t0 + 128 + sch * 8);
            }
        }

        // ---- S^T = K . Q^T, in halves of 32 keys ----
        #pragma unroll
        for (int mh = 0; mh < 2; ++mh) {
            short8 kf[2][2];
            #pragma unroll
            for (int mi = 0; mi < 2; ++mi)
                #pragma unroll
                for (int kk = 0; kk < 2; ++kk) {
                    const int rr = (mh * 2 + mi) * 16 + l15;
                    kf[mi][kk] = *(const short8*)&Kc[rr * 64 + (((kk * 4 + quad) ^ (rr & 7)) << 3)];
                }
            f32x4 st[2][2];
            #pragma unroll
            for (int mi = 0; mi < 2; ++mi)
                #pragma unroll
                for (int nb = 0; nb < 2; ++nb) st[mi][nb] = fzero;
            __builtin_amdgcn_s_setprio(1);
            #pragma unroll
            for (int kk = 0; kk < 2; ++kk)
                #pragma unroll
                for (int mi = 0; mi < 2; ++mi)
                    #pragma unroll
                    for (int nb = 0; nb < 2; ++nb)
                        st[mi][nb] = __builtin_amdgcn_mfma_f32_16x16x32_bf16(
                            kf[mi][kk], qf[nb][kk], st[mi][nb], 0, 0, 0);
            __builtin_amdgcn_s_setprio(0);

            // p = exp2(s); lane-local row sums; pack 4 keys -> one b64 store
            #pragma unroll
            for (int mi = 0; mi < 2; ++mi)
                #pragma unroll
                for (int nb = 0; nb < 2; ++nb) {
                    float p0 = __builtin_amdgcn_exp2f(st[mi][nb][0]);
                    float p1 = __builtin_amdgcn_exp2f(st[mi][nb][1]);
                    float p2 = __builtin_amdgcn_exp2f(st[mi][nb][2]);
                    float p3 = __builtin_amdgcn_exp2f(st[mi][nb][3]);
                    lacc[nb] += (p0 + p1) + (p2 + p3);
                    uint2 u;
                    u.x = pk_bf16(p0, p1);
                    u.y = pk_bf16(p2, p3);
                    const int row = wave * 32 + nb * 16 + l15;
                    const int c8  = (mh * 2 + mi) * 4 + quad;          // 8B chunk
                    *(uint2*)&Ps[row * 64 + ((c8 ^ (l15 & 14)) << 2)] = u;
                }
        }

        // ---- O^T += V^T(A) . P^T(B) ----  (Ps rows wave-private: no barrier)
        #pragma unroll
        for (int kk = 0; kk < 2; ++kk) {
            short8 vf[4], pf[2];
            #pragma unroll
            for (int mb = 0; mb < 4; ++mb) {
                const int rv = mb * 16 + l15;
                vf[mb] = *(const short8*)&Vc[rv * 64 + (((kk * 4 + quad) ^ (rv & 7)) << 3)];
            }
            #pragma unroll
            for (int nb = 0; nb < 2; ++nb) {
                const int rp = wave * 32 + nb * 16 + l15;
                pf[nb] = *(const short8*)&Ps[rp * 64 + (((kk * 8 + quad * 2) ^ (l15 & 14)) << 2)];
            }
            __builtin_amdgcn_s_setprio(1);
            #pragma unroll
            for (int mb = 0; mb < 4; ++mb)
                #pragma unroll
                for (int nb = 0; nb < 2; ++nb)
                    o[mb][nb] = __builtin_amdgcn_mfma_f32_16x16x32_bf16(
                        vf[mb], pf[nb], o[mb][nb], 0, 0, 0);
            __builtin_amdgcn_s_setprio(0);
        }

        __syncthreads();   // next buffer staged + this buffer's reads done
    }

    // deferred l reduction (across the 4 quads sharing l15) + normalize + store
    #pragma unroll
    for (int nb = 0; nb < 2; ++nb) {
        float l = lacc[nb];
        l += __shfl_xor(l, 16);
        l += __shfl_xor(l, 32);
        const float inv = 1.f / l;
        const int row = s0 + wave * 32 + nb * 16 + l15;
        #pragma unroll
        for (int mb = 0; mb < 4; ++mb) {
            uint2 u;
            u.x = pk_bf16(o[mb][nb][0] * inv, o[mb][nb][1] * inv);
            u.y = pk_bf16(o[mb][nb][2] * inv, o[mb][nb][3] * inv);
            *(uint2*)&hp[base + (size_t)row * D_DIM + mb * 16 + quad * 4] = u;
        }
    }
}

// ---------------------------------------------------------------------------
extern "C" void kernel_launch(void* const* d_in, const int* in_sizes, int n_in,
                              void* d_out, int out_size, void* d_ws, size_t ws_size,
                              hipStream_t stream) {
    const float* Q  = (const float*)d_in[0];
    const float* K  = (const float*)d_in[1];
    const float* V  = (const float*)d_in[2];
    const float* Wq = (const float*)d_in[3];
    const float* Wk = (const float*)d_in[4];
    const float* Wv = (const float*)d_in[5];
    const float* Wo = (const float*)d_in[6];

    const int NBSD = 8388608;   // B*S*D
    const int NW   = 1048576;   // D*D

    unsigned short* Qb  = (unsigned short*)d_ws;
    unsigned short* Kb  = Qb  + NBSD;
    unsigned short* Vb  = Kb  + NBSD;
    unsigned short* Wqb = Vb  + NBSD;
    unsigned short* Wkb = Wqb + NW;
    unsigned short* Wvb = Wkb + NW;
    unsigned short* Wob = Wvb + NW;
    unsigned short* qp  = Wob + NW;
    unsigned short* kp  = qp  + NBSD;
    unsigned short* vtp = kp  + NBSD;   // V^T layout [(b*H+h)*64+dk][s]
    unsigned short* hb  = vtp + NBSD;   // total ~118 MB

    // 3*4096 blocks (Q,K,V) + 4*512 blocks (weights) in one launch
    f2b_all<<<14336, 256, 0, stream>>>(Q, K, V, Wq, Wk, Wv, Wo,
                                       Qb, Kb, Vb, Wqb, Wkb, Wvb, Wob);

    const int M = B_NUM * S_LEN;          // 8192
    dim3 gqkv(D_DIM / 128, M / 128, 3);   // 8 x 64 x 3
    gemm_qkv<<<gqkv, 256, 0, stream>>>(Qb, Kb, Vb, Wqb, Wkb, Wvb, qp, kp, vtp);

    flash_mfma<<<512, 512, 0, stream>>>(qp, kp, vtp, hb);

    gemm_out<<<dim3(D_DIM / 128, M / 128), 256, 0, stream>>>(hb, Wob, (float*)d_out);
}

// Round 6
// 382.762 us; speedup vs baseline: 1.1108x; 1.0906x over previous
//
#include <hip/hip_runtime.h>
#include <hip/hip_bf16.h>
#include <math.h>

#define B_NUM 2
#define S_LEN 4096
#define D_DIM 1024
#define H_NUM 16
#define DKH   64

typedef __attribute__((ext_vector_type(8))) short short8;   // 8 bf16 = 4 VGPR (MFMA A/B frag)
typedef __attribute__((ext_vector_type(4))) float f32x4;    // MFMA C/D frag

__device__ __forceinline__ unsigned short f2bf(float f) {
    unsigned int u = __float_as_uint(f);
    u = (u + 0x7FFFu + ((u >> 16) & 1u)) >> 16;   // RNE
    return (unsigned short)u;
}

// packed f32x2 -> bf16x2, RNE
__device__ __forceinline__ unsigned pk_bf16(float lo, float hi) {
    __hip_bfloat162 h = __float22bfloat162_rn(make_float2(lo, hi));
    unsigned u; __builtin_memcpy(&u, &h, 4); return u;
}

// async global->LDS, 16B per lane (GEMM staging)
__device__ __forceinline__ void async_ld16(const unsigned short* g, unsigned short* l) {
    __builtin_amdgcn_global_load_lds(
        (const __attribute__((address_space(1))) unsigned int*)g,
        (__attribute__((address_space(3))) unsigned int*)l, 16, 0, 0);
}

// ---------------------------------------------------------------------------
// fused fp32 -> bf16 convert, ALL 7 arrays in one launch (fewer gaps).
// blocks 0..12287: Q/K/V (4096 blocks each); 12288..14335: Wq/Wk/Wv/Wo (512 each)
// ---------------------------------------------------------------------------
__global__ __launch_bounds__(256) void f2b_all(
    const float* __restrict__ x0, const float* __restrict__ x1, const float* __restrict__ x2,
    const float* __restrict__ x3, const float* __restrict__ x4, const float* __restrict__ x5,
    const float* __restrict__ x6,
    unsigned short* __restrict__ y0, unsigned short* __restrict__ y1, unsigned short* __restrict__ y2,
    unsigned short* __restrict__ y3, unsigned short* __restrict__ y4, unsigned short* __restrict__ y5,
    unsigned short* __restrict__ y6)
{
    const float* xs[7] = { x0, x1, x2, x3, x4, x5, x6 };
    unsigned short* ys[7] = { y0, y1, y2, y3, y4, y5, y6 };
    const int id = blockIdx.x;
    int a, off;
    if (id < 12288) { a = id >> 12;             off = id & 4095; }
    else            { a = 3 + ((id - 12288) >> 9); off = (id - 12288) & 511; }
    const float* x = xs[a];
    unsigned short* y = ys[a];
    int i = (off * 256 + threadIdx.x) * 8;
    float4 va = *(const float4*)(x + i);
    float4 vb = *(const float4*)(x + i + 4);
    unsigned t[4] = { pk_bf16(va.x, va.y), pk_bf16(va.z, va.w),
                      pk_bf16(vb.x, vb.y), pk_bf16(vb.z, vb.w) };
    *(uint4*)(y + i) = *(const uint4*)t;
}

// ---------------------------------------------------------------------------
// GEMM core v2 (unchanged from v9): 128x128 tile, LDS double-buffered,
// stage t+1 issued before compute of t, ONE __syncthreads per K-step.
// ---------------------------------------------------------------------------
__device__ __forceinline__ void gemm_core2(
    const unsigned short* __restrict__ A, const unsigned short* __restrict__ Wt,
    unsigned short* As, unsigned short* Bs,     // each 2*128*32 elems
    int m0, int n0, int K, f32x4 (&acc)[4][4])
{
    const int tid  = threadIdx.x;
    const int lane = tid & 63;
    const int wave = tid >> 6;
    const int quad = lane >> 4;
    const int l15  = lane & 15;
    const int wm = (wave >> 1) * 64;
    const int wn = (wave & 1) * 64;

    const int c0 = tid, c1 = tid + 256;
    const unsigned short* A0 = A  + (size_t)(m0 + (c0 >> 2)) * K + (c0 & 3) * 8;
    const unsigned short* A1 = A  + (size_t)(m0 + (c1 >> 2)) * K + (c1 & 3) * 8;
    const unsigned short* W0 = Wt + (size_t)(n0 + (c0 >> 2)) * K + (c0 & 3) * 8;
    const unsigned short* W1 = Wt + (size_t)(n0 + (c1 >> 2)) * K + (c1 & 3) * 8;

    // prologue: stage K-step 0 into half 0
    async_ld16(A0, &As[c0 * 8]);
    async_ld16(A1, &As[c1 * 8]);
    async_ld16(W0, &Bs[c0 * 8]);
    async_ld16(W1, &Bs[c1 * 8]);
    __syncthreads();

    for (int k0 = 0; k0 < K; k0 += 32) {
        const int cur = (k0 >> 5) & 1;
        const int cb  = cur * 4096;          // current half base (elems)

        // issue STAGE of step t+1 into the other half (in flight across MFMA)
        if (k0 + 32 < K) {
            const int nb = (cur ^ 1) * 4096;
            async_ld16(A0 + k0 + 32, &As[nb + c0 * 8]);
            async_ld16(A1 + k0 + 32, &As[nb + c1 * 8]);
            async_ld16(W0 + k0 + 32, &Bs[nb + c0 * 8]);
            async_ld16(W1 + k0 + 32, &Bs[nb + c1 * 8]);
        }

        short8 af[4], bfr[4];
        #pragma unroll
        for (int i = 0; i < 4; ++i)
            af[i] = *(const short8*)&As[cb + (wm + i * 16 + l15) * 32 + quad * 8];
        #pragma unroll
        for (int j = 0; j < 4; ++j)
            bfr[j] = *(const short8*)&Bs[cb + (wn + j * 16 + l15) * 32 + quad * 8];
        __builtin_amdgcn_s_setprio(1);
        #pragma unroll
        for (int i = 0; i < 4; ++i)
            #pragma unroll
            for (int j = 0; j < 4; ++j)
                acc[i][j] = __builtin_amdgcn_mfma_f32_16x16x32_bf16(af[i], bfr[j], acc[i][j], 0, 0, 0);
        __builtin_amdgcn_s_setprio(0);

        __syncthreads();   // drains vmcnt (next half staged) + seals cur reads
    }
}

// ---------------------------------------------------------------------------
// Fused QKV projection with XCD-AWARE block decode (T1). Flattened grid of
// 1536 blocks: xcd = bx&7 owns m-tiles [xcd*8, xcd*8+8) for ALL n and z,
// n-fastest then m then z. Per-XCD L2 working set per z = A-chunk 2.1 MB
// (1024 rows) + W 2.1 MB ~= the 4 MB L2, so A/W panel re-reads (8x / 64x)
// become L2 hits instead of ~800 MB of Infinity-Cache traffic. Bijective
// (1536 = 8*192). z==2 (V) writes V^T layout vt[(b*H+h)*64+dk][s] via
// packed b64 stores. q-projection folds (1/8)*log2(e) for exp2 softmax.
// ---------------------------------------------------------------------------
__global__ __launch_bounds__(256) void gemm_qkv(
    const unsigned short* __restrict__ Qb, const unsigned short* __restrict__ Kb,
    const unsigned short* __restrict__ Vb,
    const unsigned short* __restrict__ Wq, const unsigned short* __restrict__ Wk,
    const unsigned short* __restrict__ Wv,
    unsigned short* __restrict__ qo, unsigned short* __restrict__ ko,
    unsigned short* __restrict__ vto)
{
    __shared__ unsigned short As[2 * 128 * 32];
    __shared__ unsigned short Bs[2 * 128 * 32];

    // XCD-aware decode: bx -> (z, m-tile, n-tile)
    const int bx   = blockIdx.x;
    const int xcd  = bx & 7;
    const int slot = bx >> 3;          // 0..191
    const int z    = slot >> 6;        // 0..2  (slot/64)
    const int rem  = slot & 63;        // 0..63
    const int mt   = xcd * 8 + (rem >> 3);   // 0..63
    const int nt   = rem & 7;                // 0..7
    const int m0 = mt * 128;
    const int n0 = nt * 128;

    const unsigned short* A  = (z == 0) ? Qb : (z == 1) ? Kb : Vb;
    const unsigned short* Wt = (z == 0) ? Wq : (z == 1) ? Wk : Wv;
    const float scale = (z == 0) ? 0.125f * 1.4426950408889634f : 1.0f;

    const f32x4 fzero = {0.f, 0.f, 0.f, 0.f};
    f32x4 acc[4][4];
    #pragma unroll
    for (int i = 0; i < 4; ++i)
        #pragma unroll
        for (int j = 0; j < 4; ++j) acc[i][j] = fzero;

    gemm_core2(A, Wt, As, Bs, m0, n0, D_DIM, acc);

    const int lane = threadIdx.x & 63;
    const int wave = threadIdx.x >> 6;
    const int quad = lane >> 4;
    const int l15  = lane & 15;
    const int wm = (wave >> 1) * 64;
    const int wn = (wave & 1) * 64;

    if (z < 2) {
        unsigned short* out = (z == 0) ? qo : ko;
        #pragma unroll
        for (int i = 0; i < 4; ++i)
            #pragma unroll
            for (int j = 0; j < 4; ++j)
                #pragma unroll
                for (int r = 0; r < 4; ++r) {
                    const int row = m0 + wm + i * 16 + quad * 4 + r;
                    const int col = n0 + wn + j * 16 + l15;
                    out[(size_t)row * D_DIM + col] = f2bf(acc[i][j][r] * scale);
                }
    } else {
        // V^T: 4 accumulator regs = 4 consecutive s for one (h,dk) -> b64 store
        #pragma unroll
        for (int i = 0; i < 4; ++i)
            #pragma unroll
            for (int j = 0; j < 4; ++j) {
                const int row = m0 + wm + i * 16 + quad * 4;   // s-global base (r=0)
                const int col = n0 + wn + j * 16 + l15;        // h*64 + dk
                const int bb = row >> 12, ss = row & (S_LEN - 1);
                uint2 u;
                u.x = pk_bf16(acc[i][j][0], acc[i][j][1]);
                u.y = pk_bf16(acc[i][j][2], acc[i][j][3]);
                *(uint2*)&vto[((size_t)(bb * H_NUM * DKH) + col) * S_LEN + ss] = u;
            }
    }
}

// ---------------------------------------------------------------------------
// Output-projection GEMM (fp32 out), gemm_core2, XCD-aware decode (T1).
// 512 blocks: xcd = bx&7 owns m-tiles [xcd*8, xcd*8+8) for all n.
// ---------------------------------------------------------------------------
__global__ __launch_bounds__(256) void gemm_out(
    const unsigned short* __restrict__ A, const unsigned short* __restrict__ Wt,
    float* __restrict__ C)
{
    __shared__ unsigned short As[2 * 128 * 32];
    __shared__ unsigned short Bs[2 * 128 * 32];

    const int bx   = blockIdx.x;
    const int xcd  = bx & 7;
    const int slot = bx >> 3;          // 0..63
    const int mt   = xcd * 8 + (slot >> 3);
    const int nt   = slot & 7;
    const int m0 = mt * 128;
    const int n0 = nt * 128;

    const f32x4 fzero = {0.f, 0.f, 0.f, 0.f};
    f32x4 acc[4][4];
    #pragma unroll
    for (int i = 0; i < 4; ++i)
        #pragma unroll
        for (int j = 0; j < 4; ++j) acc[i][j] = fzero;

    gemm_core2(A, Wt, As, Bs, m0, n0, D_DIM, acc);

    const int lane = threadIdx.x & 63;
    const int wave = threadIdx.x >> 6;
    const int quad = lane >> 4;
    const int l15  = lane & 15;
    const int wm = (wave >> 1) * 64;
    const int wn = (wave & 1) * 64;

    #pragma unroll
    for (int i = 0; i < 4; ++i)
        #pragma unroll
        for (int j = 0; j < 4; ++j)
            #pragma unroll
            for (int r = 0; r < 4; ++r) {
                const int row = m0 + wm + i * 16 + quad * 4 + r;
                const int col = n0 + wn + j * 16 + l15;
                C[(size_t)row * D_DIM + col] = acc[i][j][r];
            }
}

// ---------------------------------------------------------------------------
// MFMA flash attention v7 (unchanged: 168 us, 818 TF).
// BR=256 per block, BC=64, grid 512, 512 threads (8 waves), each wave owns
// 32 q-rows. Ks/Vt double-buffered, one barrier per chunk, global prefetch
// one iteration ahead. S^T = K(A).Q^T(B); P packs to one b64 LDS store;
// lane-local row sums reduced with 2 shfl_xor at the end. PV: O^T =
// V^T(A).P^T(B), V pre-transposed in global by the V-GEMM. No-max exp2
// softmax. XOR swizzles keep LDS ops <=2-way. XCD-swizzled block decode.
// LDS: Ks 2x8K + Vt 2x8K + Ps 32K = 64 KB -> 2 blocks/CU, 16 waves/CU.
// ---------------------------------------------------------------------------
__global__ __launch_bounds__(512, 4) void flash_mfma(
    const unsigned short* __restrict__ q, const unsigned short* __restrict__ k,
    const unsigned short* __restrict__ vt, unsigned short* __restrict__ hp)
{
    __shared__ unsigned short Ks[2][64 * 64];    // [key][dk]   16B-chunk swizzled
    __shared__ unsigned short Vt[2][64 * 64];    // [dk][key]   16B-chunk swizzled
    __shared__ unsigned short Ps[256 * 64];      // [qrow][key] 8B-chunk even-swizzled

    const int tid  = threadIdx.x;
    const int lane = tid & 63;
    const int wave = tid >> 6;          // 0..7
    const int quad = lane >> 4;
    const int l15  = lane & 15;

    // XCD-aware decode: all 16 s-tiles of one (b,h) land on one XCD (d%8 map)
    const int bx   = blockIdx.x;
    const int xcd  = bx & 7, slot = bx >> 3;
    const int g    = xcd + 8 * (slot >> 4);   // (b*H + h), 0..31
    const int s0   = (slot & 15) * 256;
    const int b    = g >> 4, h = g & 15;
    const size_t base = (size_t)b * (S_LEN * D_DIM) + (size_t)h * DKH;
    const size_t vtb  = (size_t)g * (DKH * S_LEN);

    // Q fragments (B-operand): qf[nblk][kk], n = qrow = l15; wave owns 32 rows
    short8 qf[2][2];
    #pragma unroll
    for (int nb = 0; nb < 2; ++nb)
        #pragma unroll
        for (int kk = 0; kk < 2; ++kk)
            qf[nb][kk] = *(const short8*)(q + base +
                (size_t)(s0 + wave * 32 + nb * 16 + l15) * D_DIM + kk * 32 + quad * 8);

    const f32x4 fzero = {0.f, 0.f, 0.f, 0.f};
    f32x4 o[4][2];               // O^T: row=dk (quad*4+r), col=qrow (l15)
    float lacc[2] = {};
    #pragma unroll
    for (int i = 0; i < 4; ++i)
        #pragma unroll
        for (int j = 0; j < 2; ++j) o[i][j] = fzero;

    const int sr  = tid >> 3;          // staging row 0..63
    const int sch = tid & 7;           // 16B chunk index
    const int swz = ((sch ^ (sr & 7)) << 3);

    uint4 kpre, vpre;
    // ---- prologue: stage chunk 0 into buf 0, then issue prefetch of chunk 1
    {
        kpre = *(const uint4*)(k + base + (size_t)sr * D_DIM + sch * 8);
        vpre = *(const uint4*)(vt + vtb + (size_t)sr * S_LEN + sch * 8);
        *(uint4*)&Ks[0][sr * 64 + swz] = kpre;
        *(uint4*)&Vt[0][sr * 64 + swz] = vpre;
        kpre = *(const uint4*)(k + base + (size_t)(64 + sr) * D_DIM + sch * 8);
        vpre = *(const uint4*)(vt + vtb + (size_t)sr * S_LEN + 64 + sch * 8);
    }
    __syncthreads();

    for (int t0 = 0; t0 < S_LEN; t0 += 64) {
        const int cur = (t0 >> 6) & 1;
        const unsigned short* Kc = Ks[cur];
        const unsigned short* Vc = Vt[cur];

        // ---- stage chunk t+1 into the other buffer (data prefetched last
        // iter; vmcnt wait effectively free), then issue prefetch of t+2.
        if (t0 + 64 < S_LEN) {
            *(uint4*)&Ks[cur ^ 1][sr * 64 + swz] = kpre;
            *(uint4*)&Vt[cur ^ 1][sr * 64 + swz] = vpre;
            if (t0 + 128 < S_LEN) {
                kpre = *(const uint4*)(k + base + (size_t)(t0 + 128 + sr) * D_DIM + sch * 8);
                vpre = *(const uint4*)(vt + vtb + (size_t)sr * S_LEN + t0 + 128 + sch * 8);
            }
        }

        // ---- S^T = K . Q^T, in halves of 32 keys ----
        #pragma unroll
        for (int mh = 0; mh < 2; ++mh) {
            short8 kf[2][2];
            #pragma unroll
            for (int mi = 0; mi < 2; ++mi)
                #pragma unroll
                for (int kk = 0; kk < 2; ++kk) {
                    const int rr = (mh * 2 + mi) * 16 + l15;
                    kf[mi][kk] = *(const short8*)&Kc[rr * 64 + (((kk * 4 + quad) ^ (rr & 7)) << 3)];
                }
            f32x4 st[2][2];
            #pragma unroll
            for (int mi = 0; mi < 2; ++mi)
                #pragma unroll
                for (int nb = 0; nb < 2; ++nb) st[mi][nb] = fzero;
            __builtin_amdgcn_s_setprio(1);
            #pragma unroll
            for (int kk = 0; kk < 2; ++kk)
                #pragma unroll
                for (int mi = 0; mi < 2; ++mi)
                    #pragma unroll
                    for (int nb = 0; nb < 2; ++nb)
                        st[mi][nb] = __builtin_amdgcn_mfma_f32_16x16x32_bf16(
                            kf[mi][kk], qf[nb][kk], st[mi][nb], 0, 0, 0);
            __builtin_amdgcn_s_setprio(0);

            // p = exp2(s); lane-local row sums; pack 4 keys -> one b64 store
            #pragma unroll
            for (int mi = 0; mi < 2; ++mi)
                #pragma unroll
                for (int nb = 0; nb < 2; ++nb) {
                    float p0 = __builtin_amdgcn_exp2f(st[mi][nb][0]);
                    float p1 = __builtin_amdgcn_exp2f(st[mi][nb][1]);
                    float p2 = __builtin_amdgcn_exp2f(st[mi][nb][2]);
                    float p3 = __builtin_amdgcn_exp2f(st[mi][nb][3]);
                    lacc[nb] += (p0 + p1) + (p2 + p3);
                    uint2 u;
                    u.x = pk_bf16(p0, p1);
                    u.y = pk_bf16(p2, p3);
                    const int row = wave * 32 + nb * 16 + l15;
                    const int c8  = (mh * 2 + mi) * 4 + quad;          // 8B chunk
                    *(uint2*)&Ps[row * 64 + ((c8 ^ (l15 & 14)) << 2)] = u;
                }
        }

        // ---- O^T += V^T(A) . P^T(B) ----  (Ps rows wave-private: no barrier)
        #pragma unroll
        for (int kk = 0; kk < 2; ++kk) {
            short8 vf[4], pf[2];
            #pragma unroll
            for (int mb = 0; mb < 4; ++mb) {
                const int rv = mb * 16 + l15;
                vf[mb] = *(const short8*)&Vc[rv * 64 + (((kk * 4 + quad) ^ (rv & 7)) << 3)];
            }
            #pragma unroll
            for (int nb = 0; nb < 2; ++nb) {
                const int rp = wave * 32 + nb * 16 + l15;
                pf[nb] = *(const short8*)&Ps[rp * 64 + (((kk * 8 + quad * 2) ^ (l15 & 14)) << 2)];
            }
            __builtin_amdgcn_s_setprio(1);
            #pragma unroll
            for (int mb = 0; mb < 4; ++mb)
                #pragma unroll
                for (int nb = 0; nb < 2; ++nb)
                    o[mb][nb] = __builtin_amdgcn_mfma_f32_16x16x32_bf16(
                        vf[mb], pf[nb], o[mb][nb], 0, 0, 0);
            __builtin_amdgcn_s_setprio(0);
        }

        __syncthreads();   // next buffer staged + this buffer's reads done
    }

    // deferred l reduction (across the 4 quads sharing l15) + normalize + store
    #pragma unroll
    for (int nb = 0; nb < 2; ++nb) {
        float l = lacc[nb];
        l += __shfl_xor(l, 16);
        l += __shfl_xor(l, 32);
        const float inv = 1.f / l;
        const int row = s0 + wave * 32 + nb * 16 + l15;
        #pragma unroll
        for (int mb = 0; mb < 4; ++mb) {
            uint2 u;
            u.x = pk_bf16(o[mb][nb][0] * inv, o[mb][nb][1] * inv);
            u.y = pk_bf16(o[mb][nb][2] * inv, o[mb][nb][3] * inv);
            *(uint2*)&hp[base + (size_t)row * D_DIM + mb * 16 + quad * 4] = u;
        }
    }
}

// ---------------------------------------------------------------------------
extern "C" void kernel_launch(void* const* d_in, const int* in_sizes, int n_in,
                              void* d_out, int out_size, void* d_ws, size_t ws_size,
                              hipStream_t stream) {
    const float* Q  = (const float*)d_in[0];
    const float* K  = (const float*)d_in[1];
    const float* V  = (const float*)d_in[2];
    const float* Wq = (const float*)d_in[3];
    const float* Wk = (const float*)d_in[4];
    const float* Wv = (const float*)d_in[5];
    const float* Wo = (const float*)d_in[6];

    const int NBSD = 8388608;   // B*S*D
    const int NW   = 1048576;   // D*D

    unsigned short* Qb  = (unsigned short*)d_ws;
    unsigned short* Kb  = Qb  + NBSD;
    unsigned short* Vb  = Kb  + NBSD;
    unsigned short* Wqb = Vb  + NBSD;
    unsigned short* Wkb = Wqb + NW;
    unsigned short* Wvb = Wkb + NW;
    unsigned short* Wob = Wvb + NW;
    unsigned short* qp  = Wob + NW;
    unsigned short* kp  = qp  + NBSD;
    unsigned short* vtp = kp  + NBSD;   // V^T layout [(b*H+h)*64+dk][s]
    unsigned short* hb  = vtp + NBSD;   // total ~118 MB

    // 3*4096 blocks (Q,K,V) + 4*512 blocks (weights) in one launch
    f2b_all<<<14336, 256, 0, stream>>>(Q, K, V, Wq, Wk, Wv, Wo,
                                       Qb, Kb, Vb, Wqb, Wkb, Wvb, Wob);

    // XCD-swizzled 1D grid: 8 xcd * (3 z * 8 m * 8 n) = 1536 blocks
    gemm_qkv<<<1536, 256, 0, stream>>>(Qb, Kb, Vb, Wqb, Wkb, Wvb, qp, kp, vtp);

    flash_mfma<<<512, 512, 0, stream>>>(qp, kp, vtp, hb);

    // XCD-swizzled 1D grid: 8 xcd * (8 m * 8 n) = 512 blocks
    gemm_out<<<512, 256, 0, stream>>>(hb, Wob, (float*)d_out);
}